// Round 2
// baseline (318.358 us; speedup 1.0000x reference)
//
#include <hip/hip_runtime.h>
#include <stdint.h>

// RBF kernel matrix: out[i,j] = exp(-gamma * max(||x_i||^2 + ||y_j||^2 - 2 x_i.y_j, 0))
// N=M=8192, D=256, fp32 in/out. GEMM via bf16 MFMA (no fp32 MFMA on CDNA4).
//
// R2 change: fragment-major LDS layout. global_load_lds forces LDS slot =
// wave-base + lane*16, but the per-lane GLOBAL address is free — so we stage
// each (16-row-group x K32) fragment set into one 1 KiB chunk in exact MFMA
// lane order. Fragment ds_read_b128 becomes base + lane*16 (contiguous,
// conflict-free) instead of 64B-row-stride reads (8-way bank conflict, 2.94x).

typedef __attribute__((ext_vector_type(4))) float f32x4;
typedef __attribute__((ext_vector_type(8))) __bf16 bf16x8;

#define NN 8192
#define MM 8192
#define DD 256
#define BK 32

// ---------------------------------------------------------------------------
// Prep: per-row squared norm (fp32) + bf16 conversion of x and y into d_ws.
// One wave per row: 64 lanes x float4 = 256 elements.
// ---------------------------------------------------------------------------
__global__ __launch_bounds__(256) void prep_kernel(
    const float* __restrict__ x, const float* __restrict__ y,
    unsigned short* __restrict__ xb, unsigned short* __restrict__ yb,
    float* __restrict__ xsq, float* __restrict__ ysq) {
  const int lane = threadIdx.x & 63;
  const int row  = blockIdx.x * 4 + (threadIdx.x >> 6);  // 4 waves/block

  const float* src = x;
  unsigned short* dst = xb;
  float* sq = xsq;
  int r = row;
  if (row >= NN) { src = y; dst = yb; sq = ysq; r = row - NN; }

  const float4 v = reinterpret_cast<const float4*>(src + (size_t)r * DD)[lane];
  float s = v.x * v.x + v.y * v.y + v.z * v.z + v.w * v.w;

  union { __bf16 b[4]; ushort4 u; } cv;
  cv.b[0] = (__bf16)v.x;
  cv.b[1] = (__bf16)v.y;
  cv.b[2] = (__bf16)v.z;
  cv.b[3] = (__bf16)v.w;
  reinterpret_cast<ushort4*>(dst + (size_t)r * DD)[lane] = cv.u;

  #pragma unroll
  for (int o = 32; o > 0; o >>= 1) s += __shfl_down(s, o);
  if (lane == 0) sq[r] = s;
}

// ---------------------------------------------------------------------------
// GEMM + fused RBF epilogue. 128x128 tile / block, 256 threads = 4 waves in
// 2x2; each wave computes 64x64 via 4x4 grid of 16x16x32 bf16 MFMA tiles.
//
// LDS layout (fragment-major): chunk g (g=0..7) = 1 KiB holding row-group
// [g*16, g*16+16) x K-window [kk, kk+32):
//   byte offset lane*16 within chunk g  <->  A[g*16 + (lane&15)][kk + (lane>>4)*8 ..+7]
// Fragment read for tile i: bf16x8 at As + (group*512 + lane*8) elements —
// the whole wave reads 1 KiB contiguous: zero bank conflicts.
// ---------------------------------------------------------------------------
__global__ __launch_bounds__(256, 2) void rbf_gemm_kernel(
    const unsigned short* __restrict__ xb, const unsigned short* __restrict__ yb,
    const float* __restrict__ xsq, const float* __restrict__ ysq,
    const float* __restrict__ gamma, float* __restrict__ out) {
  __shared__ unsigned short As[128 * BK];  // 8 KB, 8 chunks of 1 KiB
  __shared__ unsigned short Bs[128 * BK];  // 8 KB

  const int tid   = threadIdx.x;
  const int lane  = tid & 63;
  const int wave  = tid >> 6;
  const int waveM = wave >> 1;  // 2x2 wave grid
  const int waveN = wave & 1;
  const int row0  = blockIdx.y * 128;
  const int col0  = blockIdx.x * 128;

  f32x4 acc[4][4] = {};

  // Staging source mapping (fragment-major): lane covers row (lane&15) of the
  // chunk's 16-row group, K-segment (lane>>4)*8 (16 B). Same global 64 B-per-
  // row gather pattern as row-major staging, only lane assignment differs.
  const int srow = lane & 15;         // row within 16-row group
  const int sseg = (lane >> 4) * 8;   // element offset within K-window

  for (int kk = 0; kk < DD; kk += BK) {
    __syncthreads();  // previous iteration's ds_reads done before overwrite
    #pragma unroll
    for (int q = 0; q < 2; ++q) {
      const int c = wave * 2 + q;  // wave-uniform chunk id, 8 chunks = 128 rows
      const unsigned short* ga =
          xb + (size_t)(row0 + c * 16 + srow) * DD + kk + sseg;
      __builtin_amdgcn_global_load_lds(
          (const __attribute__((address_space(1))) void*)ga,
          (__attribute__((address_space(3))) void*)(As + c * 512), 16, 0, 0);
      const unsigned short* gb =
          yb + (size_t)(col0 + c * 16 + srow) * DD + kk + sseg;
      __builtin_amdgcn_global_load_lds(
          (const __attribute__((address_space(1))) void*)gb,
          (__attribute__((address_space(3))) void*)(Bs + c * 512), 16, 0, 0);
    }
    __syncthreads();  // staging complete

    // Fragment loads: contiguous 1 KiB per wave — conflict-free.
    bf16x8 a[4], b[4];
    #pragma unroll
    for (int i = 0; i < 4; ++i)
      a[i] = *reinterpret_cast<const bf16x8*>(
          As + (waveM * 4 + i) * 512 + lane * 8);
    #pragma unroll
    for (int j = 0; j < 4; ++j)
      b[j] = *reinterpret_cast<const bf16x8*>(
          Bs + (waveN * 4 + j) * 512 + lane * 8);

    #pragma unroll
    for (int i = 0; i < 4; ++i)
      #pragma unroll
      for (int j = 0; j < 4; ++j)
        acc[i][j] =
            __builtin_amdgcn_mfma_f32_16x16x32_bf16(a[i], b[j], acc[i][j], 0, 0, 0);
  }

  // Epilogue: C/D layout col=lane&15, row=(lane>>4)*4+reg (m89-verified).
  const float g = gamma[0];
  const int colb = col0 + waveN * 64 + (lane & 15);
  float ysv[4];
  #pragma unroll
  for (int j = 0; j < 4; ++j) ysv[j] = ysq[colb + j * 16];

  #pragma unroll
  for (int i = 0; i < 4; ++i) {
    #pragma unroll
    for (int r = 0; r < 4; ++r) {
      const int row = row0 + waveM * 64 + i * 16 + (lane >> 4) * 4 + r;
      const float xsv = xsq[row];
      #pragma unroll
      for (int j = 0; j < 4; ++j) {
        float s = xsv + ysv[j] - 2.0f * acc[i][j][r];
        s = fmaxf(s, 0.0f);
        out[(size_t)row * MM + colb + j * 16] = __expf(-g * s);
      }
    }
  }
}

// ---------------------------------------------------------------------------
extern "C" void kernel_launch(void* const* d_in, const int* in_sizes, int n_in,
                              void* d_out, int out_size, void* d_ws, size_t ws_size,
                              hipStream_t stream) {
  const float* x     = (const float*)d_in[0];
  const float* y     = (const float*)d_in[1];
  const float* gamma = (const float*)d_in[2];
  float* out = (float*)d_out;

  // Workspace layout: xb[N*D] bf16 | yb[M*D] bf16 | xsq[N] f32 | ysq[M] f32
  unsigned short* xb = (unsigned short*)d_ws;
  unsigned short* yb = xb + (size_t)NN * DD;
  float* xsq = (float*)(yb + (size_t)MM * DD);
  float* ysq = xsq + NN;

  prep_kernel<<<(NN + MM) / 4, 256, 0, stream>>>(x, y, xb, yb, xsq, ysq);

  dim3 grid(MM / 128, NN / 128);
  rbf_gemm_kernel<<<grid, 256, 0, stream>>>(xb, yb, xsq, ysq, gamma, out);
}

// Round 3
// 299.038 us; speedup vs baseline: 1.0646x; 1.0646x over previous
//
#include <hip/hip_runtime.h>
#include <stdint.h>

// RBF kernel matrix: out[i,j] = exp(-gamma * max(||x_i||^2 + ||y_j||^2 - 2 x_i.y_j, 0))
// N=M=8192, D=256, fp32 in/out. GEMM via bf16 MFMA (no fp32 MFMA on CDNA4).
//
// R3: XOR-swizzled LDS layout. R1 (row-major) had 4-way bank-quad conflicts on
// fragment ds_read_b128 (row stride 64 B -> lanes alternate bank-quads 0/4).
// R2 (fragment-major) fixed reads but scattered the staging global pattern
// (64x 16B txns/wave) and regressed. Here: K-segment s of row r is stored at
// seg position s ^ ((r>>1)&3). Staging 4-lane groups still cover the same
// 64 B run (segs merely permuted) -> R1 coalescing; fragment reads hit
// bank-quads (fm*4 + p) % 8 = perfect octet permutation -> conflict-free.

typedef __attribute__((ext_vector_type(4))) float f32x4;
typedef __attribute__((ext_vector_type(8))) __bf16 bf16x8;

#define NN 8192
#define MM 8192
#define DD 256
#define BK 32

// ---------------------------------------------------------------------------
// Prep: per-row squared norm (fp32) + bf16 conversion of x and y into d_ws.
// One wave per row: 64 lanes x float4 = 256 elements.
// ---------------------------------------------------------------------------
__global__ __launch_bounds__(256) void prep_kernel(
    const float* __restrict__ x, const float* __restrict__ y,
    unsigned short* __restrict__ xb, unsigned short* __restrict__ yb,
    float* __restrict__ xsq, float* __restrict__ ysq) {
  const int lane = threadIdx.x & 63;
  const int row  = blockIdx.x * 4 + (threadIdx.x >> 6);  // 4 waves/block

  const float* src = x;
  unsigned short* dst = xb;
  float* sq = xsq;
  int r = row;
  if (row >= NN) { src = y; dst = yb; sq = ysq; r = row - NN; }

  const float4 v = reinterpret_cast<const float4*>(src + (size_t)r * DD)[lane];
  float s = v.x * v.x + v.y * v.y + v.z * v.z + v.w * v.w;

  union { __bf16 b[4]; ushort4 u; } cv;
  cv.b[0] = (__bf16)v.x;
  cv.b[1] = (__bf16)v.y;
  cv.b[2] = (__bf16)v.z;
  cv.b[3] = (__bf16)v.w;
  reinterpret_cast<ushort4*>(dst + (size_t)r * DD)[lane] = cv.u;

  #pragma unroll
  for (int o = 32; o > 0; o >>= 1) s += __shfl_down(s, o);
  if (lane == 0) sq[r] = s;
}

// ---------------------------------------------------------------------------
// GEMM + fused RBF epilogue. 128x128 tile / block, 256 threads = 4 waves in
// 2x2; each wave computes 64x64 via 4x4 grid of 16x16x32 bf16 MFMA tiles.
//
// LDS chunk c (1 KiB) = rows [c*16,c*16+16) x K-window [kk,kk+32), row-major
// with segs swizzled: byte (r&15)*64 + (s^((r>>1)&3))*16 holds seg s of row r.
// ---------------------------------------------------------------------------
__global__ __launch_bounds__(256, 2) void rbf_gemm_kernel(
    const unsigned short* __restrict__ xb, const unsigned short* __restrict__ yb,
    const float* __restrict__ xsq, const float* __restrict__ ysq,
    const float* __restrict__ gamma, float* __restrict__ out) {
  __shared__ unsigned short As[128 * BK];  // 8 KB, 8 chunks of 1 KiB
  __shared__ unsigned short Bs[128 * BK];  // 8 KB

  const int tid   = threadIdx.x;
  const int lane  = tid & 63;
  const int wave  = tid >> 6;
  const int waveM = wave >> 1;  // 2x2 wave grid
  const int waveN = wave & 1;
  const int row0  = blockIdx.y * 128;
  const int col0  = blockIdx.x * 128;

  f32x4 acc[4][4] = {};

  // Staging: lane covers row crow = lane>>2 of the chunk, LDS seg position
  // sp = lane&3; it must fetch global seg s = sp ^ ((crow>>1)&3). The 4-lane
  // group still covers the same 64 B run (perm within run) -> coalesced.
  const int crow = lane >> 2;
  const int sseg = ((lane & 3) ^ ((crow >> 1) & 3)) * 8;  // element offset

  // Fragment read offset (elements, within a chunk): row fm = lane&15 wants
  // k-seg sg = lane>>4, stored at position sg ^ ((fm>>1)&3).
  const int fm  = lane & 15;
  const int aoff = fm * 32 + (((lane >> 4) ^ ((fm >> 1) & 3)) * 8);

  for (int kk = 0; kk < DD; kk += BK) {
    __syncthreads();  // previous iteration's ds_reads done before overwrite
    #pragma unroll
    for (int q = 0; q < 2; ++q) {
      const int c = wave * 2 + q;  // wave-uniform chunk id, 8 chunks = 128 rows
      const unsigned short* ga =
          xb + (size_t)(row0 + c * 16 + crow) * DD + kk + sseg;
      __builtin_amdgcn_global_load_lds(
          (const __attribute__((address_space(1))) void*)ga,
          (__attribute__((address_space(3))) void*)(As + c * 512), 16, 0, 0);
      const unsigned short* gb =
          yb + (size_t)(col0 + c * 16 + crow) * DD + kk + sseg;
      __builtin_amdgcn_global_load_lds(
          (const __attribute__((address_space(1))) void*)gb,
          (__attribute__((address_space(3))) void*)(Bs + c * 512), 16, 0, 0);
    }
    __syncthreads();  // staging complete

    bf16x8 a[4], b[4];
    #pragma unroll
    for (int i = 0; i < 4; ++i)
      a[i] = *reinterpret_cast<const bf16x8*>(
          As + (waveM * 4 + i) * 512 + aoff);
    #pragma unroll
    for (int j = 0; j < 4; ++j)
      b[j] = *reinterpret_cast<const bf16x8*>(
          Bs + (waveN * 4 + j) * 512 + aoff);

    #pragma unroll
    for (int i = 0; i < 4; ++i)
      #pragma unroll
      for (int j = 0; j < 4; ++j)
        acc[i][j] =
            __builtin_amdgcn_mfma_f32_16x16x32_bf16(a[i], b[j], acc[i][j], 0, 0, 0);
  }

  // Epilogue: C/D layout col=lane&15, row=(lane>>4)*4+reg (m89-verified).
  const float g = gamma[0];
  const int colb = col0 + waveN * 64 + (lane & 15);
  float ysv[4];
  #pragma unroll
  for (int j = 0; j < 4; ++j) ysv[j] = ysq[colb + j * 16];

  #pragma unroll
  for (int i = 0; i < 4; ++i) {
    #pragma unroll
    for (int r = 0; r < 4; ++r) {
      const int row = row0 + waveM * 64 + i * 16 + (lane >> 4) * 4 + r;
      const float xsv = xsq[row];
      #pragma unroll
      for (int j = 0; j < 4; ++j) {
        float s = xsv + ysv[j] - 2.0f * acc[i][j][r];
        s = fmaxf(s, 0.0f);
        out[(size_t)row * MM + colb + j * 16] = __expf(-g * s);
      }
    }
  }
}

// ---------------------------------------------------------------------------
extern "C" void kernel_launch(void* const* d_in, const int* in_sizes, int n_in,
                              void* d_out, int out_size, void* d_ws, size_t ws_size,
                              hipStream_t stream) {
  const float* x     = (const float*)d_in[0];
  const float* y     = (const float*)d_in[1];
  const float* gamma = (const float*)d_in[2];
  float* out = (float*)d_out;

  // Workspace layout: xb[N*D] bf16 | yb[M*D] bf16 | xsq[N] f32 | ysq[M] f32
  unsigned short* xb = (unsigned short*)d_ws;
  unsigned short* yb = xb + (size_t)NN * DD;
  float* xsq = (float*)(yb + (size_t)MM * DD);
  float* ysq = xsq + NN;

  prep_kernel<<<(NN + MM) / 4, 256, 0, stream>>>(x, y, xb, yb, xsq, ysq);

  dim3 grid(MM / 128, NN / 128);
  rbf_gemm_kernel<<<grid, 256, 0, stream>>>(xb, yb, xsq, ysq, gamma, out);
}